// Round 6
// baseline (578.204 us; speedup 1.0000x reference)
//
#include <hip/hip_runtime.h>
#include <hip/hip_bf16.h>
#include <math.h>

#define NN 150000
#define EE 600000
#define GG 5000
#define NI 16
#define EI 8
#define GFD 32
#define HH 64
#define CC 40

#define W2ROW 1056
#define FPAD 68
#define WNODE 128          // nodes per window/block in k1
#define NWIN ((NN + WNODE - 1) / WNODE)
#define NBLK ((NN + 1023) / 1024)   // scan level-1 blocks

typedef __attribute__((ext_vector_type(8))) short short8v;
typedef __attribute__((ext_vector_type(16))) float f32x16;

__device__ __forceinline__ unsigned short f2bf(float f) {
    __hip_bfloat16 h = __float2bfloat16(f);
    return __builtin_bit_cast(unsigned short, h);
}
__device__ __forceinline__ float bf2f(unsigned short u) {
    return __uint_as_float(((unsigned)u) << 16);
}
__device__ __forceinline__ unsigned cvtpk(float lo, float hi) {
    unsigned r;
    asm("v_cvt_pk_bf16_f32 %0, %1, %2" : "=v"(r) : "v"(lo), "v"(hi));
    return r;
}
__device__ __forceinline__ short8v zfrag(float eh, const float (&xs)[8]) {
    union { short8v v; unsigned u[4]; } A;
    #pragma unroll
    for (int q = 0; q < 4; ++q)
        A.u[q] = cvtpk(eh * xs[2 * q], eh * xs[2 * q + 1]);
    return A.v;
}

// ---------------- K0: prep bf16 weight views ----------------
__global__ void k0_prep(const float* __restrict__ W_e2, const float* __restrict__ b_e2,
                        const float* __restrict__ W_fc1, const float* __restrict__ W_np,
                        unsigned short* __restrict__ W2T,
                        unsigned short* __restrict__ W1aT,
                        unsigned short* __restrict__ W_npT)
{
    int idx = blockIdx.x * 256 + threadIdx.x;
    if (idx < 64 * W2ROW) {
        int h = idx / W2ROW, j = idx % W2ROW;
        float v = 0.f;
        if (j < 1024)      { int k = j >> 4, i = j & 15; v = W_e2[k * 1024 + i * 64 + h]; }
        else if (j < 1040) { int i = j - 1024;           v = b_e2[i * 64 + h]; }
        W2T[idx] = f2bf(v);
    } else if (idx < 64 * W2ROW + 4096) {
        int i = idx - 64 * W2ROW;
        int h = i >> 6, k = i & 63;
        W1aT[i] = f2bf(W_fc1[k * 64 + h]);
    } else if (idx < 64 * W2ROW + 8192) {
        int i = idx - 64 * W2ROW - 4096;
        int c = i >> 6, h = i & 63;
        W_npT[i] = f2bf(c < CC ? W_np[h * CC + c] : 0.f);
    }
}

// ---------------- counting sort of edges by dst ----------------
__global__ void kA_hist(const int* __restrict__ ei, int* __restrict__ cnt)
{
    int e = blockIdx.x * 256 + threadIdx.x;
    if (e < EE) atomicAdd(&cnt[ei[EE + e]], 1);
}

__global__ void kB_scan1(const int* __restrict__ cnt, int* __restrict__ base,
                         int* __restrict__ bsum)
{
    __shared__ int sS[256];
    int b = blockIdx.x, t = threadIdx.x;
    int i0 = b * 1024 + t * 4;
    int v0 = (i0 + 0 < NN) ? cnt[i0 + 0] : 0;
    int v1 = (i0 + 1 < NN) ? cnt[i0 + 1] : 0;
    int v2 = (i0 + 2 < NN) ? cnt[i0 + 2] : 0;
    int v3 = (i0 + 3 < NN) ? cnt[i0 + 3] : 0;
    int tot = v0 + v1 + v2 + v3;
    sS[t] = tot;
    __syncthreads();
    int acc = tot;
    for (int off = 1; off < 256; off <<= 1) {
        int xv = (t >= off) ? sS[t - off] : 0;
        __syncthreads();
        acc += xv;
        sS[t] = acc;
        __syncthreads();
    }
    int run = acc - tot;
    if (i0 + 0 < NN) base[i0 + 0] = run; run += v0;
    if (i0 + 1 < NN) base[i0 + 1] = run; run += v1;
    if (i0 + 2 < NN) base[i0 + 2] = run; run += v2;
    if (i0 + 3 < NN) base[i0 + 3] = run;
    if (t == 255) bsum[b] = acc;
}

__global__ void kC_scan2(int* __restrict__ bsum)
{
    __shared__ int sS[256];
    int t = threadIdx.x;
    int v = (t < NBLK) ? bsum[t] : 0;
    sS[t] = v;
    __syncthreads();
    int acc = v;
    for (int off = 1; off < 256; off <<= 1) {
        int xv = (t >= off) ? sS[t - off] : 0;
        __syncthreads();
        acc += xv;
        sS[t] = acc;
        __syncthreads();
    }
    if (t < NBLK) bsum[t] = acc - v;   // exclusive
}

__global__ void kD_scan3(int* __restrict__ base, const int* __restrict__ bsum,
                         int* __restrict__ cursor)
{
    int i = blockIdx.x * 256 + threadIdx.x;
    if (i < NN) {
        int v = base[i] + bsum[i >> 10];
        base[i] = v;
        cursor[i] = v;
    }
    if (i == 0) base[NN] = EE;
}

__global__ void kE_scat(const int* __restrict__ ei, int* __restrict__ cursor,
                        int* __restrict__ perm)
{
    int e = blockIdx.x * 256 + threadIdx.x;
    if (e < EE) {
        int d = ei[EE + e];
        int s = atomicAdd(&cursor[d], 1);
        perm[s] = e;
    }
}

// ---------------- K1: windowed edge MLP + MFMA z-GEMM + LDS reduce ----------------
__device__ __forceinline__ void mfma_step(
    const unsigned short (&sEHT)[65][256], int c, int pf,
    const unsigned short* __restrict__ Bq0, const unsigned short* __restrict__ Bq1,
    int mb, int mr, const float (&xs0)[8], const float (&xs1)[8],
    short8v& curb0, short8v& curb1,
    f32x16& acc00, f32x16& acc01, f32x16& acc10, f32x16& acc11)
{
    short8v n0 = *(const short8v*)(Bq0 + pf * 16);
    short8v n1 = *(const short8v*)(Bq1 + pf * 16);
    int cc = (c & 31) << 1;
    float eh0 = bf2f(sEHT[c][(mb + mr) ^ cc]);
    float eh1 = bf2f(sEHT[c][(mb + 32 + mr) ^ cc]);
    short8v a0 = zfrag(eh0, xs0);
    short8v a1 = zfrag(eh1, xs1);
    __builtin_amdgcn_s_setprio(1);
    acc00 = __builtin_amdgcn_mfma_f32_32x32x16_bf16(a0, curb0, acc00, 0, 0, 0);
    acc01 = __builtin_amdgcn_mfma_f32_32x32x16_bf16(a0, curb1, acc01, 0, 0, 0);
    acc10 = __builtin_amdgcn_mfma_f32_32x32x16_bf16(a1, curb0, acc10, 0, 0, 0);
    acc11 = __builtin_amdgcn_mfma_f32_32x32x16_bf16(a1, curb1, acc11, 0, 0, 0);
    __builtin_amdgcn_s_setprio(0);
    curb0 = n0; curb1 = n1;
}

__global__ __launch_bounds__(256, 2) void k1_win(
    const float* __restrict__ x, const int* __restrict__ ei,
    const float* __restrict__ ea,
    const float* __restrict__ W_e1, const float* __restrict__ b_e1,
    const unsigned short* __restrict__ W2T,
    const int* __restrict__ base, const int* __restrict__ perm,
    float* __restrict__ agg)
{
    __shared__ float sAgg[WNODE][64];
    __shared__ unsigned short sEHT[65][256];
    __shared__ float sEA[256][8];
    __shared__ int sDst[256];

    const int t = threadIdx.x;
    const int nbase = blockIdx.x * WNODE;
    const int nend = (nbase + WNODE < NN) ? nbase + WNODE : NN;
    const int s_slot = base[nbase];
    const int e_slot = base[nend];

    // zero window accumulator
    {
        float4 z = make_float4(0.f, 0.f, 0.f, 0.f);
        float* p = &sAgg[0][0];
        #pragma unroll
        for (int q = 0; q < 8; ++q) *(float4*)&p[q * 1024 + t * 4] = z;
    }

    const int lane = t & 63;
    const int w = t >> 6;
    const int mr = lane & 31;
    const int half = lane >> 5;
    const int mb = w * 64;
    const int k = t & 63;

    // W_e1 column for this thread's k (reused across chunks)
    float w1[8];
    float b1 = b_e1[k];
    #pragma unroll
    for (int j = 0; j < 8; ++j) w1[j] = W_e1[j * 64 + k];

    const unsigned short* Bq0 = W2T + (size_t)mr * W2ROW + half * 8;
    const unsigned short* Bq1 = Bq0 + 32 * W2ROW;

    for (int cb = s_slot; cb < e_slot; cb += 256) {
        __syncthreads();   // protect LDS staging vs previous chunk's readers

        // ---- stage perm/dst/ea for this chunk ----
        {
            int slot = cb + t;
            int pe = (slot < e_slot) ? perm[slot] : -1;
            sDst[t] = (pe >= 0) ? ei[EE + pe] - nbase : -1;
            float4 z = make_float4(0.f, 0.f, 0.f, 0.f);
            if (pe >= 0) {
                const float4* eap = (const float4*)(ea + (size_t)pe * EI);
                *(float4*)&sEA[t][0] = eap[0];
                *(float4*)&sEA[t][4] = eap[1];
            } else {
                *(float4*)&sEA[t][0] = z;
                *(float4*)&sEA[t][4] = z;
            }
            sEHT[64][t] = (unsigned short)0x3F80;   // bias row eh = 1.0
        }
        __syncthreads();

        // ---- edge MLP layer 1 -> sEHT (transposed, swizzled) ----
        {
            #pragma unroll 4
            for (int r = 0; r < 64; ++r) {
                int e = w * 64 + r;
                float4 u0 = *(const float4*)&sEA[e][0];
                float4 u1 = *(const float4*)&sEA[e][4];
                float v = b1;
                v = fmaf(u0.x, w1[0], v); v = fmaf(u0.y, w1[1], v);
                v = fmaf(u0.z, w1[2], v); v = fmaf(u0.w, w1[3], v);
                v = fmaf(u1.x, w1[4], v); v = fmaf(u1.y, w1[5], v);
                v = fmaf(u1.z, w1[6], v); v = fmaf(u1.w, w1[7], v);
                v = fmaxf(v, 0.f);
                sEHT[k][e ^ ((k & 31) << 1)] = f2bf(v);
            }
        }

        // ---- per-lane xs gather ----
        float xs0[8], xs1[8];
        {
            int slot0 = cb + mb + mr;
            int slot1 = cb + mb + 32 + mr;
            int pe0 = (slot0 < e_slot) ? perm[slot0] : -1;
            int pe1 = (slot1 < e_slot) ? perm[slot1] : -1;
            if (pe0 >= 0) {
                int s0 = ei[pe0];
                const float4* xp = (const float4*)(x + (size_t)s0 * NI + half * 8);
                float4 u0 = xp[0], u1 = xp[1];
                xs0[0]=u0.x; xs0[1]=u0.y; xs0[2]=u0.z; xs0[3]=u0.w;
                xs0[4]=u1.x; xs0[5]=u1.y; xs0[6]=u1.z; xs0[7]=u1.w;
            } else {
                #pragma unroll
                for (int q = 0; q < 8; ++q) xs0[q] = 0.f;
            }
            if (pe1 >= 0) {
                int s1 = ei[pe1];
                const float4* xp = (const float4*)(x + (size_t)s1 * NI + half * 8);
                float4 u0 = xp[0], u1 = xp[1];
                xs1[0]=u0.x; xs1[1]=u0.y; xs1[2]=u0.z; xs1[3]=u0.w;
                xs1[4]=u1.x; xs1[5]=u1.y; xs1[6]=u1.z; xs1[7]=u1.w;
            } else {
                #pragma unroll
                for (int q = 0; q < 8; ++q) xs1[q] = 0.f;
            }
        }
        __syncthreads();   // sEHT ready

        f32x16 acc00, acc01, acc10, acc11;
        #pragma unroll
        for (int r = 0; r < 16; ++r) { acc00[r]=0.f; acc01[r]=0.f; acc10[r]=0.f; acc11[r]=0.f; }

        short8v bA0 = *(const short8v*)(Bq0);
        short8v bA1 = *(const short8v*)(Bq1);
        short8v bB0 = *(const short8v*)(Bq0 + 16);
        short8v bB1 = *(const short8v*)(Bq1 + 16);

        #pragma unroll 2
        for (int c = 0; c < 64; c += 2) {
            mfma_step(sEHT, c,     c + 2, Bq0, Bq1, mb, mr, xs0, xs1, bA0, bA1, acc00, acc01, acc10, acc11);
            mfma_step(sEHT, c + 1, c + 3, Bq0, Bq1, mb, mr, xs0, xs1, bB0, bB1, acc00, acc01, acc10, acc11);
        }
        mfma_step(sEHT, 64, 64, Bq0, Bq1, mb, mr, xs0, xs1, bA0, bA1, acc00, acc01, acc10, acc11);

        // ---- epilogue: LDS reduce (ds_add_f32, conflict-free) ----
        #pragma unroll
        for (int r = 0; r < 16; ++r) {
            int row = (r & 3) + 8 * (r >> 2) + 4 * half;
            int d0 = sDst[mb + row];
            int d1 = sDst[mb + 32 + row];
            if (d0 >= 0) {
                atomicAdd(&sAgg[d0][mr],      acc00[r]);
                atomicAdd(&sAgg[d0][32 + mr], acc01[r]);
            }
            if (d1 >= 0) {
                atomicAdd(&sAgg[d1][mr],      acc10[r]);
                atomicAdd(&sAgg[d1][32 + mr], acc11[r]);
            }
        }
    }

    __syncthreads();
    // ---- coalesced writeout: each node owned by exactly this block ----
    {
        const float* sa = &sAgg[0][0];
        #pragma unroll
        for (int q = 0; q < 8; ++q) {
            int i = q * 1024 + t * 4;
            int gi = nbase * 64 + i;
            if (gi < NN * 64)
                *(float4*)&agg[gi] = *(const float4*)&sa[i];
        }
    }
}

// ---------------- K2: mean + root + relu (in place over agg) + gate ----------------
__global__ __launch_bounds__(256) void k2_node(
    const float* __restrict__ x, const float* __restrict__ root,
    const float* __restrict__ conv_bias, const int* __restrict__ cnt,
    float* __restrict__ hn,
    const float* __restrict__ Wg, const float* __restrict__ bg,
    float* __restrict__ gate)
{
    int t = threadIdx.x;
    int n = blockIdx.x * 4 + (t >> 6);
    int h = t & 63;
    float inv = 1.0f / fmaxf((float)cnt[n], 1.0f);
    float v = hn[(size_t)n * 64 + h] * inv + conv_bias[h];
    const float* xp = x + (size_t)n * NI;
    #pragma unroll
    for (int i = 0; i < NI; ++i) v += xp[i] * root[i * 64 + h];
    v = fmaxf(v, 0.f);
    hn[(size_t)n * 64 + h] = v;
    float gv = v * Wg[h];
    #pragma unroll
    for (int off = 32; off; off >>= 1) gv += __shfl_xor(gv, off);
    if (h == 0) gate[n] = gv + bg[0];
}

// ---------------- K3: per-graph pooling + pg/sg precompute ----------------
__device__ __forceinline__ int lbound(const int* __restrict__ b, int v) {
    int lo = 0, hi = NN;
    while (lo < hi) { int mid = (lo + hi) >> 1; if (b[mid] < v) lo = mid + 1; else hi = mid; }
    return lo;
}

__global__ __launch_bounds__(64) void k3_pool(
    const float* __restrict__ gate, const int* __restrict__ batch,
    const float* __restrict__ hn, const float* __restrict__ pocket,
    const float* __restrict__ W_fc1, const float* __restrict__ b_fc1,
    const float* __restrict__ W_sp, const float* __restrict__ b_sp,
    float* __restrict__ pg, float* __restrict__ sg)
{
    int g = blockIdx.x;
    int lane = threadIdx.x;
    int s = lbound(batch, g);
    int e = lbound(batch, g + 1);

    float gcv = 0.f;
    if (e > s) {
        float m = -INFINITY;
        for (int n = s + lane; n < e; n += 64) m = fmaxf(m, gate[n]);
        #pragma unroll
        for (int off = 32; off; off >>= 1) m = fmaxf(m, __shfl_xor(m, off));
        float acc = 0.f, den = 0.f;
        for (int n = s; n < e; ++n) {
            float ev = expf(gate[n] - m);
            den += ev;
            acc += ev * hn[(size_t)n * 64 + lane];
        }
        gcv = acc / den;
    }

    float sv = gcv * W_sp[lane];
    #pragma unroll
    for (int off = 32; off; off >>= 1) sv += __shfl_xor(sv, off);
    if (lane == 0) sg[g] = 1.f / (1.f + expf(-(sv + b_sp[0])));

    float pk = (lane < GFD) ? pocket[(size_t)g * GFD + lane] : 0.f;
    float pgv = b_fc1[lane];
    #pragma unroll 8
    for (int kk = 0; kk < 64; ++kk)
        pgv = fmaf(__shfl(gcv, kk), W_fc1[(64 + kk) * 64 + lane], pgv);
    #pragma unroll 8
    for (int kk = 0; kk < 32; ++kk)
        pgv = fmaf(__shfl(pk, kk), W_fc1[(128 + kk) * 64 + lane], pgv);
    pg[(size_t)g * 64 + lane] = pgv;
}

// ---------------- K4: MFMA head ----------------
__global__ __launch_bounds__(256, 4) void k4_mfma(
    const float* __restrict__ hn, const int* __restrict__ batch,
    const float* __restrict__ pg, const float* __restrict__ sg,
    const unsigned short* __restrict__ W1aT, const unsigned short* __restrict__ W_npT,
    const float* __restrict__ b_np,
    float* __restrict__ out_np, float* __restrict__ out_stop)
{
    __shared__ __align__(16) float sF[4][32][FPAD];
    __shared__ int sB[128];

    const int t = threadIdx.x;
    const int wv = t >> 6, lane = t & 63;
    const int mr = lane & 31, half = lane >> 5;
    const int nb = blockIdx.x * 128;

    if (t < 128) {
        int n = nb + t;
        sB[t] = (n < NN) ? batch[n] : 0;
    }

    const int node = nb + wv * 32 + mr;

    f32x16 acc0, acc1;
    #pragma unroll
    for (int r = 0; r < 16; ++r) { acc0[r] = 0.f; acc1[r] = 0.f; }

    #pragma unroll
    for (int c = 0; c < 4; ++c) {
        short8v a;
        if (node < NN) {
            const float4* hp = (const float4*)(hn + (size_t)node * 64 + c * 16 + half * 8);
            float4 u0 = hp[0], u1 = hp[1];
            union { short8v v; unsigned u[4]; } A;
            A.u[0] = cvtpk(u0.x, u0.y); A.u[1] = cvtpk(u0.z, u0.w);
            A.u[2] = cvtpk(u1.x, u1.y); A.u[3] = cvtpk(u1.z, u1.w);
            a = A.v;
        } else {
            #pragma unroll
            for (int q = 0; q < 8; ++q) a[q] = 0;
        }
        short8v b0 = *(const short8v*)(W1aT + (size_t)mr * 64        + c * 16 + half * 8);
        short8v b1 = *(const short8v*)(W1aT + (size_t)(mr + 32) * 64 + c * 16 + half * 8);
        acc0 = __builtin_amdgcn_mfma_f32_32x32x16_bf16(a, b0, acc0, 0, 0, 0);
        acc1 = __builtin_amdgcn_mfma_f32_32x32x16_bf16(a, b1, acc1, 0, 0, 0);
    }
    __syncthreads();

    #pragma unroll
    for (int r = 0; r < 16; ++r) {
        int row = (r & 3) + 8 * (r >> 2) + 4 * half;
        int g = sB[wv * 32 + row];
        float p0 = pg[(size_t)g * 64 + mr];
        float p1 = pg[(size_t)g * 64 + 32 + mr];
        sF[wv][row][mr]      = fmaxf(acc0[r] + p0, 0.f);
        sF[wv][row][32 + mr] = fmaxf(acc1[r] + p1, 0.f);
    }

    f32x16 acc2, acc3;
    #pragma unroll
    for (int r = 0; r < 16; ++r) { acc2[r] = 0.f; acc3[r] = 0.f; }

    #pragma unroll
    for (int c = 0; c < 4; ++c) {
        const float* fp = &sF[wv][mr][c * 16 + half * 8];
        float4 u0 = *(const float4*)(fp);
        float4 u1 = *(const float4*)(fp + 4);
        union { short8v v; unsigned u[4]; } A;
        A.u[0] = cvtpk(u0.x, u0.y); A.u[1] = cvtpk(u0.z, u0.w);
        A.u[2] = cvtpk(u1.x, u1.y); A.u[3] = cvtpk(u1.z, u1.w);
        short8v a = A.v;
        short8v b0 = *(const short8v*)(W_npT + (size_t)mr * 64        + c * 16 + half * 8);
        short8v b1 = *(const short8v*)(W_npT + (size_t)(mr + 32) * 64 + c * 16 + half * 8);
        acc2 = __builtin_amdgcn_mfma_f32_32x32x16_bf16(a, b0, acc2, 0, 0, 0);
        acc3 = __builtin_amdgcn_mfma_f32_32x32x16_bf16(a, b1, acc3, 0, 0, 0);
    }

    float bn1 = b_np[mr];
    float bn2 = (mr < 8) ? b_np[32 + mr] : 0.f;

    #pragma unroll
    for (int r = 0; r < 16; ++r) {
        int row = (r & 3) + 8 * (r >> 2) + 4 * half;
        int n = nb + wv * 32 + row;
        float v1 = acc2[r] + bn1;
        float v2 = acc3[r] + bn2;
        float m = (mr < 8) ? fmaxf(v1, v2) : v1;
        #pragma unroll
        for (int off = 16; off; off >>= 1) m = fmaxf(m, __shfl_xor(m, off));
        float s = expf(v1 - m) + ((mr < 8) ? expf(v2 - m) : 0.f);
        #pragma unroll
        for (int off = 16; off; off >>= 1) s += __shfl_xor(s, off);
        float ls = m + logf(s);
        if (n < NN) {
            out_np[(size_t)n * CC + mr] = v1 - ls;
            if (mr < 8) out_np[(size_t)n * CC + 32 + mr] = v2 - ls;
            if (mr == 0) out_stop[n] = sg[sB[wv * 32 + row]];
        }
    }
}

extern "C" void kernel_launch(void* const* d_in, const int* in_sizes, int n_in,
                              void* d_out, int out_size, void* d_ws, size_t ws_size,
                              hipStream_t stream)
{
    (void)in_sizes; (void)n_in; (void)out_size; (void)ws_size;
    const float* x        = (const float*)d_in[0];
    const int*   ei       = (const int*)d_in[1];
    const float* ea       = (const float*)d_in[2];
    const int*   batch    = (const int*)d_in[3];
    const float* pocket   = (const float*)d_in[4];
    const float* W_e1     = (const float*)d_in[5];
    const float* b_e1     = (const float*)d_in[6];
    const float* W_e2     = (const float*)d_in[7];
    const float* b_e2     = (const float*)d_in[8];
    const float* root     = (const float*)d_in[9];
    const float* conv_b   = (const float*)d_in[10];
    const float* Wg       = (const float*)d_in[11];
    const float* bg       = (const float*)d_in[12];
    const float* W_fc1    = (const float*)d_in[13];
    const float* b_fc1    = (const float*)d_in[14];
    const float* W_np     = (const float*)d_in[15];
    const float* b_np     = (const float*)d_in[16];
    const float* W_sp     = (const float*)d_in[17];
    const float* b_sp     = (const float*)d_in[18];

    float* ws = (float*)d_ws;
    float* agg    = ws;                                  // NN*64 f32
    int*   cnti   = (int*)(agg + (size_t)NN * 64);       // NN
    int*   base   = cnti + NN;                           // NN+4 (padded for alignment)
    int*   bsum   = base + NN + 4;                       // 256
    int*   cursor = bsum + 256;                          // NN
    int*   perm   = cursor + NN;                         // EE
    float* gate   = (float*)(perm + EE);                 // NN
    float* pg     = gate + NN;                           // GG*64
    float* sg     = pg + (size_t)GG * 64;                // GG
    unsigned short* W2T   = (unsigned short*)(sg + GG);  // 64*W2ROW
    unsigned short* W1aT  = W2T + (size_t)64 * W2ROW;    // 64*64
    unsigned short* W_npT = W1aT + 4096;                 // 64*64

    hipMemsetAsync(cnti, 0, (size_t)NN * sizeof(int), stream);

    k0_prep<<<(64 * W2ROW + 8192 + 255) / 256, 256, 0, stream>>>(
        W_e2, b_e2, W_fc1, W_np, W2T, W1aT, W_npT);

    // counting sort of edges by dst
    kA_hist<<<(EE + 255) / 256, 256, 0, stream>>>(ei, cnti);
    kB_scan1<<<NBLK, 256, 0, stream>>>(cnti, base, bsum);
    kC_scan2<<<1, 256, 0, stream>>>(bsum);
    kD_scan3<<<(NN + 255) / 256, 256, 0, stream>>>(base, bsum, cursor);
    kE_scat<<<(EE + 255) / 256, 256, 0, stream>>>(ei, cursor, perm);

    // windowed message GEMM + LDS reduction (no global atomics)
    k1_win<<<NWIN, 256, 0, stream>>>(x, ei, ea, W_e1, b_e1, W2T, base, perm, agg);

    k2_node<<<NN / 4, 256, 0, stream>>>(x, root, conv_b, cnti, agg, Wg, bg, gate);
    k3_pool<<<GG, 64, 0, stream>>>(gate, batch, agg, pocket, W_fc1, b_fc1, W_sp, b_sp, pg, sg);

    float* out_np   = (float*)d_out;
    float* out_stop = out_np + (size_t)NN * CC;
    k4_mfma<<<(NN + 127) / 128, 256, 0, stream>>>(agg, batch, pg, sg, W1aT, W_npT, b_np,
                                                  out_np, out_stop);
}

// Round 7
// 353.779 us; speedup vs baseline: 1.6344x; 1.6344x over previous
//
#include <hip/hip_runtime.h>
#include <hip/hip_bf16.h>
#include <math.h>

#define NN 150000
#define EE 600000
#define GG 5000
#define NI 16
#define EI 8
#define GFD 32
#define HH 64
#define CC 40

#define W2ROW 1056
#define FPAD 68
#define NBLK ((NN + 1023) / 1024)   // scan level-1 blocks

typedef __attribute__((ext_vector_type(8))) short short8v;
typedef __attribute__((ext_vector_type(16))) float f32x16;

__device__ __forceinline__ unsigned short f2bf(float f) {
    __hip_bfloat16 h = __float2bfloat16(f);
    return __builtin_bit_cast(unsigned short, h);
}
__device__ __forceinline__ float bf2f(unsigned short u) {
    return __uint_as_float(((unsigned)u) << 16);
}
__device__ __forceinline__ unsigned cvtpk(float lo, float hi) {
    unsigned r;
    asm("v_cvt_pk_bf16_f32 %0, %1, %2" : "=v"(r) : "v"(lo), "v"(hi));
    return r;
}
__device__ __forceinline__ short8v zfrag(float eh, const float (&xs)[8]) {
    union { short8v v; unsigned u[4]; } A;
    #pragma unroll
    for (int q = 0; q < 4; ++q)
        A.u[q] = cvtpk(eh * xs[2 * q], eh * xs[2 * q + 1]);
    return A.v;
}

// ---------------- K0: prep bf16 weight views ----------------
__global__ void k0_prep(const float* __restrict__ W_e2, const float* __restrict__ b_e2,
                        const float* __restrict__ W_fc1, const float* __restrict__ W_np,
                        unsigned short* __restrict__ W2T,
                        unsigned short* __restrict__ W1aT,
                        unsigned short* __restrict__ W_npT)
{
    int idx = blockIdx.x * 256 + threadIdx.x;
    if (idx < 64 * W2ROW) {
        int h = idx / W2ROW, j = idx % W2ROW;
        float v = 0.f;
        if (j < 1024)      { int k = j >> 4, i = j & 15; v = W_e2[k * 1024 + i * 64 + h]; }
        else if (j < 1040) { int i = j - 1024;           v = b_e2[i * 64 + h]; }
        W2T[idx] = f2bf(v);
    } else if (idx < 64 * W2ROW + 4096) {
        int i = idx - 64 * W2ROW;
        int h = i >> 6, k = i & 63;
        W1aT[i] = f2bf(W_fc1[k * 64 + h]);
    } else if (idx < 64 * W2ROW + 8192) {
        int i = idx - 64 * W2ROW - 4096;
        int c = i >> 6, h = i & 63;
        W_npT[i] = f2bf(c < CC ? W_np[h * CC + c] : 0.f);
    }
}

// ---------------- counting sort (rank only) ----------------
__global__ void kA_hist(const int* __restrict__ ei, int* __restrict__ cnt)
{
    int e = blockIdx.x * 256 + threadIdx.x;
    if (e < EE) atomicAdd(&cnt[ei[EE + e]], 1);
}

__global__ void kB_scan1(const int* __restrict__ cnt, int* __restrict__ base,
                         int* __restrict__ bsum)
{
    __shared__ int sS[256];
    int b = blockIdx.x, t = threadIdx.x;
    int i0 = b * 1024 + t * 4;
    int v0 = (i0 + 0 < NN) ? cnt[i0 + 0] : 0;
    int v1 = (i0 + 1 < NN) ? cnt[i0 + 1] : 0;
    int v2 = (i0 + 2 < NN) ? cnt[i0 + 2] : 0;
    int v3 = (i0 + 3 < NN) ? cnt[i0 + 3] : 0;
    int tot = v0 + v1 + v2 + v3;
    sS[t] = tot;
    __syncthreads();
    int acc = tot;
    for (int off = 1; off < 256; off <<= 1) {
        int xv = (t >= off) ? sS[t - off] : 0;
        __syncthreads();
        acc += xv;
        sS[t] = acc;
        __syncthreads();
    }
    int run = acc - tot;
    if (i0 + 0 < NN) base[i0 + 0] = run; run += v0;
    if (i0 + 1 < NN) base[i0 + 1] = run; run += v1;
    if (i0 + 2 < NN) base[i0 + 2] = run; run += v2;
    if (i0 + 3 < NN) base[i0 + 3] = run;
    if (t == 255) bsum[b] = acc;
}

__global__ void kC_scan2(int* __restrict__ bsum)
{
    __shared__ int sS[256];
    int t = threadIdx.x;
    int v = (t < NBLK) ? bsum[t] : 0;
    sS[t] = v;
    __syncthreads();
    int acc = v;
    for (int off = 1; off < 256; off <<= 1) {
        int xv = (t >= off) ? sS[t - off] : 0;
        __syncthreads();
        acc += xv;
        sS[t] = acc;
        __syncthreads();
    }
    if (t < NBLK) bsum[t] = acc - v;   // exclusive
}

__global__ void kD_scan3(int* __restrict__ base, const int* __restrict__ bsum,
                         int* __restrict__ cursor)
{
    int i = blockIdx.x * 256 + threadIdx.x;
    if (i < NN) {
        int v = base[i] + bsum[i >> 10];
        base[i] = v;
        cursor[i] = v;
    }
    if (i == 0) base[NN] = EE;
}

__global__ void kE_rank(const int* __restrict__ ei, int* __restrict__ cursor,
                        int* __restrict__ rank)
{
    int e = blockIdx.x * 256 + threadIdx.x;
    if (e < EE) {
        int d = ei[EE + e];
        rank[e] = atomicAdd(&cursor[d], 1);
    }
}

// ---------------- shared MFMA inner step ----------------
__device__ __forceinline__ void mfma_step(
    const unsigned short (&sEHT)[65][256], int c, int pf,
    const unsigned short* __restrict__ Bq0, const unsigned short* __restrict__ Bq1,
    int mb, int mr, const float (&xs0)[8], const float (&xs1)[8],
    short8v& curb0, short8v& curb1,
    f32x16& acc00, f32x16& acc01, f32x16& acc10, f32x16& acc11)
{
    short8v n0 = *(const short8v*)(Bq0 + pf * 16);
    short8v n1 = *(const short8v*)(Bq1 + pf * 16);
    int cc = (c & 31) << 1;
    float eh0 = bf2f(sEHT[c][(mb + mr) ^ cc]);
    float eh1 = bf2f(sEHT[c][(mb + 32 + mr) ^ cc]);
    short8v a0 = zfrag(eh0, xs0);
    short8v a1 = zfrag(eh1, xs1);
    __builtin_amdgcn_s_setprio(1);
    acc00 = __builtin_amdgcn_mfma_f32_32x32x16_bf16(a0, curb0, acc00, 0, 0, 0);
    acc01 = __builtin_amdgcn_mfma_f32_32x32x16_bf16(a0, curb1, acc01, 0, 0, 0);
    acc10 = __builtin_amdgcn_mfma_f32_32x32x16_bf16(a1, curb0, acc10, 0, 0, 0);
    acc11 = __builtin_amdgcn_mfma_f32_32x32x16_bf16(a1, curb1, acc11, 0, 0, 0);
    __builtin_amdgcn_s_setprio(0);
    curb0 = n0; curb1 = n1;
}

// ---------------- K1: edge MLP + MFMA z-GEMM; TWOPHASE: store msg@rank, else atomic ----------------
template<bool TWOPHASE>
__global__ __launch_bounds__(256, 3) void k1_mfma(
    const float* __restrict__ x, const int* __restrict__ ei,
    const float* __restrict__ ea,
    const float* __restrict__ W_e1, const float* __restrict__ b_e1,
    const unsigned short* __restrict__ W2T,
    const int* __restrict__ rank,
    float* __restrict__ msgbuf, float* __restrict__ agg)
{
    __shared__ unsigned short sEHT[65][256];
    __shared__ int sIdx[256];     // rank (twophase) or dst (atomic)

    const int t = threadIdx.x;
    const long long eb = (long long)blockIdx.x * 256;

    {
        long long ge = eb + t;
        if (ge < EE) sIdx[t] = TWOPHASE ? rank[ge] : ei[EE + ge];
        else         sIdx[t] = -1;
        sEHT[64][t] = (unsigned short)0x3F80;   // bias row eh = 1.0
    }
    {
        const int k = t & 63;
        const int w = t >> 6;
        float w1[8];
        float b1 = b_e1[k];
        #pragma unroll
        for (int j = 0; j < 8; ++j) w1[j] = W_e1[j * 64 + k];
        #pragma unroll 4
        for (int r = 0; r < 64; ++r) {
            int e = w * 64 + r;
            long long ge = eb + e;
            float v = 0.f;
            if (ge < EE) {
                const float4* eap = (const float4*)(ea + ge * EI);
                float4 u0 = eap[0], u1 = eap[1];
                v = b1;
                v = fmaf(u0.x, w1[0], v); v = fmaf(u0.y, w1[1], v);
                v = fmaf(u0.z, w1[2], v); v = fmaf(u0.w, w1[3], v);
                v = fmaf(u1.x, w1[4], v); v = fmaf(u1.y, w1[5], v);
                v = fmaf(u1.z, w1[6], v); v = fmaf(u1.w, w1[7], v);
                v = fmaxf(v, 0.f);
            }
            sEHT[k][e ^ ((k & 31) << 1)] = f2bf(v);
        }
    }

    const int lane = t & 63;
    const int w = t >> 6;
    const int mr = lane & 31;
    const int half = lane >> 5;
    const int mb = w * 64;

    float xs0[8], xs1[8];
    {
        long long e0 = eb + mb + mr;
        long long e1 = eb + mb + 32 + mr;
        if (e0 < EE) {
            int s0 = ei[e0];
            const float4* xp = (const float4*)(x + (size_t)s0 * NI + half * 8);
            float4 u0 = xp[0], u1 = xp[1];
            xs0[0]=u0.x; xs0[1]=u0.y; xs0[2]=u0.z; xs0[3]=u0.w;
            xs0[4]=u1.x; xs0[5]=u1.y; xs0[6]=u1.z; xs0[7]=u1.w;
        } else {
            #pragma unroll
            for (int q = 0; q < 8; ++q) xs0[q] = 0.f;
        }
        if (e1 < EE) {
            int s1 = ei[e1];
            const float4* xp = (const float4*)(x + (size_t)s1 * NI + half * 8);
            float4 u0 = xp[0], u1 = xp[1];
            xs1[0]=u0.x; xs1[1]=u0.y; xs1[2]=u0.z; xs1[3]=u0.w;
            xs1[4]=u1.x; xs1[5]=u1.y; xs1[6]=u1.z; xs1[7]=u1.w;
        } else {
            #pragma unroll
            for (int q = 0; q < 8; ++q) xs1[q] = 0.f;
        }
    }
    __syncthreads();

    f32x16 acc00, acc01, acc10, acc11;
    #pragma unroll
    for (int r = 0; r < 16; ++r) { acc00[r] = 0.f; acc01[r] = 0.f; acc10[r] = 0.f; acc11[r] = 0.f; }

    const unsigned short* Bq0 = W2T + (size_t)mr * W2ROW + half * 8;
    const unsigned short* Bq1 = Bq0 + 32 * W2ROW;

    short8v bA0 = *(const short8v*)(Bq0);
    short8v bA1 = *(const short8v*)(Bq1);
    short8v bB0 = *(const short8v*)(Bq0 + 16);
    short8v bB1 = *(const short8v*)(Bq1 + 16);

    #pragma unroll 2
    for (int c = 0; c < 64; c += 2) {
        mfma_step(sEHT, c,     c + 2, Bq0, Bq1, mb, mr, xs0, xs1, bA0, bA1, acc00, acc01, acc10, acc11);
        mfma_step(sEHT, c + 1, c + 3, Bq0, Bq1, mb, mr, xs0, xs1, bB0, bB1, acc00, acc01, acc10, acc11);
    }
    mfma_step(sEHT, 64, 64, Bq0, Bq1, mb, mr, xs0, xs1, bA0, bA1, acc00, acc01, acc10, acc11);

    #pragma unroll
    for (int r = 0; r < 16; ++r) {
        int row = (r & 3) + 8 * (r >> 2) + 4 * half;
        int i0 = sIdx[mb + row];
        int i1 = sIdx[mb + 32 + row];
        if (TWOPHASE) {
            if (i0 >= 0) {
                msgbuf[(size_t)i0 * 64 + mr]      = acc00[r];
                msgbuf[(size_t)i0 * 64 + 32 + mr] = acc01[r];
            }
            if (i1 >= 0) {
                msgbuf[(size_t)i1 * 64 + mr]      = acc10[r];
                msgbuf[(size_t)i1 * 64 + 32 + mr] = acc11[r];
            }
        } else {
            if (i0 >= 0) {
                atomicAdd(&agg[(size_t)i0 * 64 + mr],      acc00[r]);
                atomicAdd(&agg[(size_t)i0 * 64 + 32 + mr], acc01[r]);
            }
            if (i1 >= 0) {
                atomicAdd(&agg[(size_t)i1 * 64 + mr],      acc10[r]);
                atomicAdd(&agg[(size_t)i1 * 64 + 32 + mr], acc11[r]);
            }
        }
    }
}

// ---------------- K2 (two-phase): stream-reduce msgbuf + mean + root + relu + gate ----------------
__global__ __launch_bounds__(256) void k2_red(
    const float* __restrict__ msgbuf, const int* __restrict__ base,
    const float* __restrict__ x, const float* __restrict__ root,
    const float* __restrict__ conv_bias,
    float* __restrict__ hn,
    const float* __restrict__ Wg, const float* __restrict__ bg,
    float* __restrict__ gate)
{
    __shared__ float sroot[16][64];
    int t = threadIdx.x;
    #pragma unroll
    for (int q = 0; q < 4; ++q) {
        int i = q * 256 + t;
        sroot[i >> 6][i & 63] = root[i];
    }
    __syncthreads();

    int n = blockIdx.x * 4 + (t >> 6);
    int lane = t & 63;
    int s = base[n], e = base[n + 1];

    float acc = 0.f;
    int slot = s;
    for (; slot + 2 <= e; slot += 2) {
        float a0 = msgbuf[(size_t)slot * 64 + lane];
        float a1 = msgbuf[(size_t)(slot + 1) * 64 + lane];
        acc += a0; acc += a1;
    }
    if (slot < e) acc += msgbuf[(size_t)slot * 64 + lane];

    float inv = 1.0f / fmaxf((float)(e - s), 1.0f);
    float v = acc * inv + conv_bias[lane];
    float xv = (lane < 16) ? x[(size_t)n * NI + lane] : 0.f;
    #pragma unroll
    for (int i = 0; i < 16; ++i)
        v = fmaf(__shfl(xv, i), sroot[i][lane], v);
    v = fmaxf(v, 0.f);
    hn[(size_t)n * 64 + lane] = v;

    float gv = v * Wg[lane];
    #pragma unroll
    for (int off = 32; off; off >>= 1) gv += __shfl_xor(gv, off);
    if (lane == 0) gate[n] = gv + bg[0];
}

// ---------------- K2 (fallback): mean + root + relu over agg ----------------
__global__ __launch_bounds__(256) void k2_node(
    const float* __restrict__ x, const float* __restrict__ root,
    const float* __restrict__ conv_bias, const int* __restrict__ cnt,
    float* __restrict__ hn,
    const float* __restrict__ Wg, const float* __restrict__ bg,
    float* __restrict__ gate)
{
    int t = threadIdx.x;
    int n = blockIdx.x * 4 + (t >> 6);
    int h = t & 63;
    float inv = 1.0f / fmaxf((float)cnt[n], 1.0f);
    float v = hn[(size_t)n * 64 + h] * inv + conv_bias[h];
    const float* xp = x + (size_t)n * NI;
    #pragma unroll
    for (int i = 0; i < NI; ++i) v += xp[i] * root[i * 64 + h];
    v = fmaxf(v, 0.f);
    hn[(size_t)n * 64 + h] = v;
    float gv = v * Wg[h];
    #pragma unroll
    for (int off = 32; off; off >>= 1) gv += __shfl_xor(gv, off);
    if (h == 0) gate[n] = gv + bg[0];
}

// ---------------- K3: per-graph pooling + pg/sg precompute ----------------
__device__ __forceinline__ int lbound(const int* __restrict__ b, int v) {
    int lo = 0, hi = NN;
    while (lo < hi) { int mid = (lo + hi) >> 1; if (b[mid] < v) lo = mid + 1; else hi = mid; }
    return lo;
}

__global__ __launch_bounds__(64) void k3_pool(
    const float* __restrict__ gate, const int* __restrict__ batch,
    const float* __restrict__ hn, const float* __restrict__ pocket,
    const float* __restrict__ W_fc1, const float* __restrict__ b_fc1,
    const float* __restrict__ W_sp, const float* __restrict__ b_sp,
    float* __restrict__ pg, float* __restrict__ sg)
{
    int g = blockIdx.x;
    int lane = threadIdx.x;
    int s = lbound(batch, g);
    int e = lbound(batch, g + 1);

    float gcv = 0.f;
    if (e > s) {
        float m = -INFINITY;
        for (int n = s + lane; n < e; n += 64) m = fmaxf(m, gate[n]);
        #pragma unroll
        for (int off = 32; off; off >>= 1) m = fmaxf(m, __shfl_xor(m, off));
        float acc = 0.f, den = 0.f;
        for (int n = s; n < e; ++n) {
            float ev = expf(gate[n] - m);
            den += ev;
            acc += ev * hn[(size_t)n * 64 + lane];
        }
        gcv = acc / den;
    }

    float sv = gcv * W_sp[lane];
    #pragma unroll
    for (int off = 32; off; off >>= 1) sv += __shfl_xor(sv, off);
    if (lane == 0) sg[g] = 1.f / (1.f + expf(-(sv + b_sp[0])));

    float pk = (lane < GFD) ? pocket[(size_t)g * GFD + lane] : 0.f;
    float pgv = b_fc1[lane];
    #pragma unroll 8
    for (int kk = 0; kk < 64; ++kk)
        pgv = fmaf(__shfl(gcv, kk), W_fc1[(64 + kk) * 64 + lane], pgv);
    #pragma unroll 8
    for (int kk = 0; kk < 32; ++kk)
        pgv = fmaf(__shfl(pk, kk), W_fc1[(128 + kk) * 64 + lane], pgv);
    pg[(size_t)g * 64 + lane] = pgv;
}

// ---------------- K4: MFMA head ----------------
__global__ __launch_bounds__(256, 4) void k4_mfma(
    const float* __restrict__ hn, const int* __restrict__ batch,
    const float* __restrict__ pg, const float* __restrict__ sg,
    const unsigned short* __restrict__ W1aT, const unsigned short* __restrict__ W_npT,
    const float* __restrict__ b_np,
    float* __restrict__ out_np, float* __restrict__ out_stop)
{
    __shared__ __align__(16) float sF[4][32][FPAD];
    __shared__ int sB[128];

    const int t = threadIdx.x;
    const int wv = t >> 6, lane = t & 63;
    const int mr = lane & 31, half = lane >> 5;
    const int nb = blockIdx.x * 128;

    if (t < 128) {
        int n = nb + t;
        sB[t] = (n < NN) ? batch[n] : 0;
    }

    const int node = nb + wv * 32 + mr;

    f32x16 acc0, acc1;
    #pragma unroll
    for (int r = 0; r < 16; ++r) { acc0[r] = 0.f; acc1[r] = 0.f; }

    #pragma unroll
    for (int c = 0; c < 4; ++c) {
        short8v a;
        if (node < NN) {
            const float4* hp = (const float4*)(hn + (size_t)node * 64 + c * 16 + half * 8);
            float4 u0 = hp[0], u1 = hp[1];
            union { short8v v; unsigned u[4]; } A;
            A.u[0] = cvtpk(u0.x, u0.y); A.u[1] = cvtpk(u0.z, u0.w);
            A.u[2] = cvtpk(u1.x, u1.y); A.u[3] = cvtpk(u1.z, u1.w);
            a = A.v;
        } else {
            #pragma unroll
            for (int q = 0; q < 8; ++q) a[q] = 0;
        }
        short8v b0 = *(const short8v*)(W1aT + (size_t)mr * 64        + c * 16 + half * 8);
        short8v b1 = *(const short8v*)(W1aT + (size_t)(mr + 32) * 64 + c * 16 + half * 8);
        acc0 = __builtin_amdgcn_mfma_f32_32x32x16_bf16(a, b0, acc0, 0, 0, 0);
        acc1 = __builtin_amdgcn_mfma_f32_32x32x16_bf16(a, b1, acc1, 0, 0, 0);
    }
    __syncthreads();

    #pragma unroll
    for (int r = 0; r < 16; ++r) {
        int row = (r & 3) + 8 * (r >> 2) + 4 * half;
        int g = sB[wv * 32 + row];
        float p0 = pg[(size_t)g * 64 + mr];
        float p1 = pg[(size_t)g * 64 + 32 + mr];
        sF[wv][row][mr]      = fmaxf(acc0[r] + p0, 0.f);
        sF[wv][row][32 + mr] = fmaxf(acc1[r] + p1, 0.f);
    }

    f32x16 acc2, acc3;
    #pragma unroll
    for (int r = 0; r < 16; ++r) { acc2[r] = 0.f; acc3[r] = 0.f; }

    #pragma unroll
    for (int c = 0; c < 4; ++c) {
        const float* fp = &sF[wv][mr][c * 16 + half * 8];
        float4 u0 = *(const float4*)(fp);
        float4 u1 = *(const float4*)(fp + 4);
        union { short8v v; unsigned u[4]; } A;
        A.u[0] = cvtpk(u0.x, u0.y); A.u[1] = cvtpk(u0.z, u0.w);
        A.u[2] = cvtpk(u1.x, u1.y); A.u[3] = cvtpk(u1.z, u1.w);
        short8v a = A.v;
        short8v b0 = *(const short8v*)(W_npT + (size_t)mr * 64        + c * 16 + half * 8);
        short8v b1 = *(const short8v*)(W_npT + (size_t)(mr + 32) * 64 + c * 16 + half * 8);
        acc2 = __builtin_amdgcn_mfma_f32_32x32x16_bf16(a, b0, acc2, 0, 0, 0);
        acc3 = __builtin_amdgcn_mfma_f32_32x32x16_bf16(a, b1, acc3, 0, 0, 0);
    }

    float bn1 = b_np[mr];
    float bn2 = (mr < 8) ? b_np[32 + mr] : 0.f;

    #pragma unroll
    for (int r = 0; r < 16; ++r) {
        int row = (r & 3) + 8 * (r >> 2) + 4 * half;
        int n = nb + wv * 32 + row;
        float v1 = acc2[r] + bn1;
        float v2 = acc3[r] + bn2;
        float m = (mr < 8) ? fmaxf(v1, v2) : v1;
        #pragma unroll
        for (int off = 16; off; off >>= 1) m = fmaxf(m, __shfl_xor(m, off));
        float s = expf(v1 - m) + ((mr < 8) ? expf(v2 - m) : 0.f);
        #pragma unroll
        for (int off = 16; off; off >>= 1) s += __shfl_xor(s, off);
        float ls = m + logf(s);
        if (n < NN) {
            out_np[(size_t)n * CC + mr] = v1 - ls;
            if (mr < 8) out_np[(size_t)n * CC + 32 + mr] = v2 - ls;
            if (mr == 0) out_stop[n] = sg[sB[wv * 32 + row]];
        }
    }
}

extern "C" void kernel_launch(void* const* d_in, const int* in_sizes, int n_in,
                              void* d_out, int out_size, void* d_ws, size_t ws_size,
                              hipStream_t stream)
{
    (void)in_sizes; (void)n_in; (void)out_size;
    const float* x        = (const float*)d_in[0];
    const int*   ei       = (const int*)d_in[1];
    const float* ea       = (const float*)d_in[2];
    const int*   batch    = (const int*)d_in[3];
    const float* pocket   = (const float*)d_in[4];
    const float* W_e1     = (const float*)d_in[5];
    const float* b_e1     = (const float*)d_in[6];
    const float* W_e2     = (const float*)d_in[7];
    const float* b_e2     = (const float*)d_in[8];
    const float* root     = (const float*)d_in[9];
    const float* conv_b   = (const float*)d_in[10];
    const float* Wg       = (const float*)d_in[11];
    const float* bg       = (const float*)d_in[12];
    const float* W_fc1    = (const float*)d_in[13];
    const float* b_fc1    = (const float*)d_in[14];
    const float* W_np     = (const float*)d_in[15];
    const float* b_np     = (const float*)d_in[16];
    const float* W_sp     = (const float*)d_in[17];
    const float* b_sp     = (const float*)d_in[18];

    char* wsb = (char*)d_ws;
    float* agg    = (float*)wsb;                         // NN*64
    int*   cnti   = (int*)(agg + (size_t)NN * 64);       // NN
    int*   base   = cnti + NN;                           // NN+4
    int*   bsum   = base + NN + 4;                       // 256
    int*   cursor = bsum + 256;                          // NN
    int*   rank   = cursor + NN;                         // EE
    float* gate   = (float*)(rank + EE);                 // NN
    float* pg     = gate + NN;                           // GG*64
    float* sg     = pg + (size_t)GG * 64;                // GG
    unsigned short* W2T   = (unsigned short*)(sg + GG);  // 64*W2ROW
    unsigned short* W1aT  = W2T + (size_t)64 * W2ROW;    // 4096
    unsigned short* W_npT = W1aT + 4096;                 // 4096
    // 256B-aligned msgbuf at the end
    size_t head = (size_t)((char*)(W_npT + 4096) - wsb);
    size_t msg_off = (head + 255) & ~(size_t)255;
    float* msgbuf = (float*)(wsb + msg_off);
    size_t need = msg_off + (size_t)EE * 64 * sizeof(float);
    const bool twophase = (ws_size >= need);

    hipMemsetAsync(cnti, 0, (size_t)NN * sizeof(int), stream);

    k0_prep<<<(64 * W2ROW + 8192 + 255) / 256, 256, 0, stream>>>(
        W_e2, b_e2, W_fc1, W_np, W2T, W1aT, W_npT);

    kA_hist<<<(EE + 255) / 256, 256, 0, stream>>>(ei, cnti);

    if (twophase) {
        kB_scan1<<<NBLK, 256, 0, stream>>>(cnti, base, bsum);
        kC_scan2<<<1, 256, 0, stream>>>(bsum);
        kD_scan3<<<(NN + 255) / 256, 256, 0, stream>>>(base, bsum, cursor);
        kE_rank<<<(EE + 255) / 256, 256, 0, stream>>>(ei, cursor, rank);

        k1_mfma<true><<<(EE + 255) / 256, 256, 0, stream>>>(
            x, ei, ea, W_e1, b_e1, W2T, rank, msgbuf, agg);
        k2_red<<<NN / 4, 256, 0, stream>>>(msgbuf, base, x, root, conv_b,
                                           agg, Wg, bg, gate);
    } else {
        hipMemsetAsync(agg, 0, (size_t)NN * 64 * sizeof(float), stream);
        k1_mfma<false><<<(EE + 255) / 256, 256, 0, stream>>>(
            x, ei, ea, W_e1, b_e1, W2T, rank, msgbuf, agg);
        k2_node<<<NN / 4, 256, 0, stream>>>(x, root, conv_b, cnti, agg, Wg, bg, gate);
    }

    k3_pool<<<GG, 64, 0, stream>>>(gate, batch, agg, pocket, W_fc1, b_fc1, W_sp, b_sp, pg, sg);

    float* out_np   = (float*)d_out;
    float* out_stop = out_np + (size_t)NN * CC;
    k4_mfma<<<(NN + 127) / 128, 256, 0, stream>>>(agg, batch, pg, sg, W1aT, W_npT, b_np,
                                                  out_np, out_stop);
}